// Round 14
// baseline (63.990 us; speedup 1.0000x reference)
//
#include <hip/hip_runtime.h>
#include <hip/hip_fp16.h>

// total = l1 + 0.5*(1 - mean(ssim3d)), volumes (4,1,128,128,128) f32
// SSIM window 11, zero-padded box sums, /11^3.
//
// 4-field formulation: A=sum(p+t), D=sum(p-t), U=sum((p+t)^2), V=sum((p-t)^2).
// 2*mu_p*mu_t=(muA^2-muD^2)/2, mu_p^2+mu_t^2=(muA^2+muD^2)/2,
// sig_p+sig_t=(U+V)*INV/2-S2, 2*sig_pt=(U-V)*INV/2-P2.
// f16 intermediates, field-PAIRED layout: G0[voxel]={A,D}, G1[voxel]={U,V}.
//
// R6: no last-block merge (device fence flushes per-XCD L2).
// R13 BUG FIXED: stage-B gather wrote vA[18] (OOB, UB) for m=9 and zeroed
// the live v[17]. Correct mapping: v[2m-1]=pr[m][0] (m>=1), v[2m]=pr[m][1]
// (m<=8); v[17] comes from pr[9][0].

#define NB 4
#define ND 128
#define NH 128
#define NW 128
#define PLANE (NH * NW)            // 16384
#define VOL (ND * PLANE)           // 2,097,152
#define VOL4 (NB * VOL)            // 8,388,608
#define K1_BLOCKS (NB * ND * 4)    // 2048 (h tiled by 32)
#define K2_BLOCKS 1024             // 8 d-chunks of 16 x 128 (b,h) groups
#define HS_F16 142                 // f16 row stride = 71 words (odd)

typedef _Float16 half2v __attribute__((ext_vector_type(2)));
typedef _Float16 half4v __attribute__((ext_vector_type(4)));
typedef float f32x2 __attribute__((ext_vector_type(2)));

// ---------------- Kernel 1: fused W+H box sums of 4 fields + L1 partials ----
// Stage A: 4 waves x 8 output rows, 2 w-cols/lane. Sliding 11-row window.
// Stage B: word = 71*row + 4*wc + m; 71*row mod 4 distinct across the wave's
//          4 row values -> disjoint bank groups, 2-way, free.
__global__ __launch_bounds__(256) void k_wh(const float* __restrict__ p,
                                            const float* __restrict__ t,
                                            _Float16* __restrict__ G0,
                                            _Float16* __restrict__ G1,
                                            float* __restrict__ l1p)
{
    __shared__ _Float16 hs[4][32][HS_F16];   // 36,352 B -> 4 blocks/CU
    __shared__ float red4[4];

    const int bid   = blockIdx.x;
    const int htile = bid & 3;
    const int d     = (bid >> 2) & 127;
    const int b     = bid >> 9;
    const int h0    = htile * 32;
    const int tid   = threadIdx.x;

    // zero the w-halo: cols 0..5 (w<0) and 134..141 (w>=128)
    for (int idx = tid; idx < 4 * 32 * 14; idx += 256) {
        const int f = idx / 448;
        const int rem = idx - f * 448;
        const int r = rem / 14;
        const int c14 = rem - r * 14;
        const int col = (c14 < 6) ? c14 : (128 + c14);
        hs[f][r][col] = (_Float16)0.f;
    }

    // ---- Stage A ----
    const int wp = tid & 63;          // lane: owns w = 2*wp, 2*wp+1
    const int c  = tid >> 6;          // wave: owns output rows hbase..hbase+7
    const int hbase = h0 + c * 8;
    const int pbase = ((b * ND + d) * NH) * NW + 2 * wp;
    const int wcol  = 2 * wp + 6;

    const f32x2 z2 = {0.f, 0.f};
    f32x2 Aw[11], Dw[11];
    f32x2 sA = z2, sD = z2, sU = z2, sV = z2;
    float l1x = 0.f, l1y = 0.f;

    // preload window rows idx 0..10 (h = hbase-5+i); guards wave-uniform
#pragma unroll
    for (int i = 0; i < 11; ++i) {
        const int h = hbase - 5 + i;
        f32x2 pv = z2, tv = z2;
        if (h >= 0) {                          // h <= hbase+5 <= 125 < 128
            pv = *(const f32x2*)&p[pbase + h * NW];
            tv = *(const f32x2*)&t[pbase + h * NW];
        }
        const f32x2 a = pv + tv, dd = pv - tv;
        Aw[i] = a; Dw[i] = dd;
        sA += a; sD += dd;
        sU += a * a; sV += dd * dd;
        if (i >= 5) {                          // owned rows hbase..hbase+5
            l1x += fabsf(dd.x);
            l1y += fabsf(dd.y);
        }
    }

#define STORE4(r) do {                                                        \
        half2v o_;                                                            \
        o_[0] = (_Float16)sA.x; o_[1] = (_Float16)sA.y;                       \
        *(half2v*)&hs[0][(r)][wcol] = o_;                                     \
        o_[0] = (_Float16)sD.x; o_[1] = (_Float16)sD.y;                       \
        *(half2v*)&hs[1][(r)][wcol] = o_;                                     \
        o_[0] = (_Float16)sU.x; o_[1] = (_Float16)sU.y;                       \
        *(half2v*)&hs[2][(r)][wcol] = o_;                                     \
        o_[0] = (_Float16)sV.x; o_[1] = (_Float16)sV.y;                       \
        *(half2v*)&hs[3][(r)][wcol] = o_;                                     \
    } while (0)

    STORE4(c * 8);
#pragma unroll
    for (int k = 1; k < 8; ++k) {
        const int h = hbase + 5 + k;           // incoming row (idx 10+k)
        f32x2 pv = z2, tv = z2;
        if (h < NH) {
            pv = *(const f32x2*)&p[pbase + h * NW];
            tv = *(const f32x2*)&t[pbase + h * NW];
        }
        const f32x2 a = pv + tv, dd = pv - tv;
        if (k <= 2) {                          // owned rows hbase+6, hbase+7
            l1x += fabsf(dd.x);
            l1y += fabsf(dd.y);
        }
        const f32x2 ao = Aw[k - 1], do_ = Dw[k - 1];
        sA += a - ao;
        sD += dd - do_;
        sU += a * a - ao * ao;
        sV += dd * dd - do_ * do_;
        STORE4(c * 8 + k);
    }
#undef STORE4

    // ---- L1 reduce: in-wave shuffle, one barrier ----
    {
        float v = l1x + l1y;
#pragma unroll
        for (int off = 32; off > 0; off >>= 1) v += __shfl_down(v, off, 64);
        if ((tid & 63) == 0) red4[tid >> 6] = v;
    }
    __syncthreads();          // publishes hs (stage A + halo) and red4
    if (tid == 0) l1p[bid] = red4[0] + red4[1] + red4[2] + red4[3];

    // ---- Stage B: W-direction sliding sums from LDS, paired f16 stores ----
    const int ho = tid >> 4;          // 0..15
    const int wc = tid & 15;          // owns w in [8*wc, 8*wc+8)

#pragma unroll
    for (int it = 0; it < 2; ++it) {
        const int row = ho + 16 * it;
        const size_t obase =
            (size_t)((b * ND + d) * NH + (h0 + row)) * NW + wc * 8;  // voxel

#pragma unroll
        for (int gp = 0; gp < 2; ++gp) {       // (A,D) -> G0 ; (U,V) -> G1
            // v[k] = H-sum at w = 8*wc - 5 + k, k = 0..17.
            // pr[m] = pair at logical cols (8wc+2m, 8wc+2m+1) = w (8wc-6+2m, 8wc-5+2m)
            // => pr[m][0] -> v[2m-1] (m>=1), pr[m][1] -> v[2m] (m<=8),
            //    v[17] = pr[9][0]. pr[0][0] and pr[9][1] unused.
            float vA[18], vB[18];
#pragma unroll
            for (int m = 0; m < 10; ++m) {
                const half2v ha = *(const half2v*)&hs[2 * gp][row][8 * wc + 2 * m];
                const half2v hb = *(const half2v*)&hs[2 * gp + 1][row][8 * wc + 2 * m];
                if (m > 0) { vA[2 * m - 1] = (float)ha[0]; vB[2 * m - 1] = (float)hb[0]; }
                if (m < 9) { vA[2 * m]     = (float)ha[1]; vB[2 * m]     = (float)hb[1]; }
            }
            float sa = 0.f, sb = 0.f;
#pragma unroll
            for (int j = 0; j < 11; ++j) { sa += vA[j]; sb += vB[j]; }
            union { _Float16 g[16]; uint4 q[2]; } o;
            o.g[0] = (_Float16)sa; o.g[1] = (_Float16)sb;
#pragma unroll
            for (int n = 1; n < 8; ++n) {
                sa += vA[10 + n] - vA[n - 1];
                sb += vB[10 + n] - vB[n - 1];
                o.g[2 * n] = (_Float16)sa; o.g[2 * n + 1] = (_Float16)sb;
            }
            _Float16* G = gp ? G1 : G0;
            *(uint4*)&G[2 * obase]     = o.q[0];
            *(uint4*)&G[2 * obase + 8] = o.q[1];
        }
    }
    // no trailing barrier: stores drain at endpgm
}

// ---------------- Kernel 2: D-direction sliding window + SSIM + reduce ------
// Register ring of the 11-plane window; paired b64 loads (2 per plane).
__global__ __launch_bounds__(256) void k_d_ssim(const _Float16* __restrict__ G0,
                                                const _Float16* __restrict__ G1,
                                                float* __restrict__ ssimp)
{
    __shared__ float red4[4];
    const float INV  = 1.0f / 1331.0f;
    const float INV2 = 1.0f / 2662.0f;
    const float C1f = 1e-4f, C2f = 9e-4f;

    const int bid = blockIdx.x;      // 1024 blocks
    const int dc  = bid & 7;         // d chunk (16 deep)
    const int tid = threadIdx.x;
    const int idx = ((bid >> 3) << 8) + tid;   // 0..32767 -> (b,h,wpair)
    const int wp = idx & 63;
    const int h  = (idx >> 6) & 127;
    const int b  = idx >> 13;
    const int d0 = dc * 16;
    const size_t base0 = (size_t)b * VOL + h * NW + wp * 2;   // voxel idx

#define LOADG(G, dd) (*(const half4v*)&(G)[2 * ((size_t)base0 + (size_t)(dd) * PLANE)])

    half4v ring0[11], ring1[11];      // {A,D} and {U,V} for 2 cols
    // rsx = col0 {A,D,U,V}; rsy = col1
    float rsx[4] = {0.f, 0.f, 0.f, 0.f};
    float rsy[4] = {0.f, 0.f, 0.f, 0.f};

#pragma unroll
    for (int o = -5; o <= 5; ++o) {
        const int dd = d0 + o;
        half4v g0, g1;
        if (dd >= 0 && dd < ND) {
            g0 = LOADG(G0, dd); g1 = LOADG(G1, dd);
        } else {
            g0 = g1 = (half4v)(_Float16)0.f;
        }
        ring0[o + 5] = g0; ring1[o + 5] = g1;
        rsx[0] += (float)g0[0]; rsx[1] += (float)g0[1];
        rsy[0] += (float)g0[2]; rsy[1] += (float)g0[3];
        rsx[2] += (float)g1[0]; rsx[3] += (float)g1[1];
        rsy[2] += (float)g1[2]; rsy[3] += (float)g1[3];
    }

    float acc = 0.f;
#pragma unroll
    for (int s = 0; s < 16; ++s) {
        {
            const float muA = rsx[0] * INV, muD = rsx[1] * INV;
            const float mAA = muA * muA, mDD = muD * muD;
            const float P2 = 0.5f * (mAA - mDD);     // 2 mu_p mu_t
            const float S2 = 0.5f * (mAA + mDD);     // mu_p^2 + mu_t^2
            const float num = (P2 + C1f) * fmaf(rsx[2] - rsx[3], INV2, C2f - P2);
            const float den = (S2 + C1f) * fmaf(rsx[2] + rsx[3], INV2, C2f - S2);
            acc = fmaf(num, __builtin_amdgcn_rcpf(den), acc);
        }
        {
            const float muA = rsy[0] * INV, muD = rsy[1] * INV;
            const float mAA = muA * muA, mDD = muD * muD;
            const float P2 = 0.5f * (mAA - mDD);
            const float S2 = 0.5f * (mAA + mDD);
            const float num = (P2 + C1f) * fmaf(rsy[2] - rsy[3], INV2, C2f - P2);
            const float den = (S2 + C1f) * fmaf(rsy[2] + rsy[3], INV2, C2f - S2);
            acc = fmaf(num, __builtin_amdgcn_rcpf(den), acc);
        }

        if (s < 15) {
            const int slot = s % 11;
            const int da = d0 + 6 + s;
            half4v n0, n1;
            if (da < ND) {
                n0 = LOADG(G0, da); n1 = LOADG(G1, da);
            } else {
                n0 = n1 = (half4v)(_Float16)0.f;
            }
            const half4v r0 = ring0[slot], r1 = ring1[slot];
            rsx[0] += (float)n0[0] - (float)r0[0];
            rsx[1] += (float)n0[1] - (float)r0[1];
            rsy[0] += (float)n0[2] - (float)r0[2];
            rsy[1] += (float)n0[3] - (float)r0[3];
            rsx[2] += (float)n1[0] - (float)r1[0];
            rsx[3] += (float)n1[1] - (float)r1[1];
            rsy[2] += (float)n1[2] - (float)r1[2];
            rsy[3] += (float)n1[3] - (float)r1[3];
            ring0[slot] = n0; ring1[slot] = n1;
        }
    }
#undef LOADG

    // in-wave shuffle reduce, one barrier
    float v = acc;
#pragma unroll
    for (int off = 32; off > 0; off >>= 1) v += __shfl_down(v, off, 64);
    if ((tid & 63) == 0) red4[tid >> 6] = v;
    __syncthreads();
    if (tid == 0) ssimp[bid] = red4[0] + red4[1] + red4[2] + red4[3];
}

// ---------------- Kernel 3: final deterministic reduction -------------------
__global__ __launch_bounds__(256) void k_final(const float* __restrict__ l1p,
                                               const float* __restrict__ sp,
                                               float* __restrict__ out)
{
    __shared__ double r1[256];
    __shared__ double r2[256];
    const int tid = threadIdx.x;
    double s1 = 0.0, s2 = 0.0;
    for (int i = tid; i < K1_BLOCKS; i += 256) s1 += (double)l1p[i];
    for (int i = tid; i < K2_BLOCKS; i += 256) s2 += (double)sp[i];
    r1[tid] = s1; r2[tid] = s2;
    __syncthreads();
    for (int s = 128; s > 0; s >>= 1) {
        if (tid < s) { r1[tid] += r1[tid + s]; r2[tid] += r2[tid + s]; }
        __syncthreads();
    }
    if (tid == 0) {
        const double N = (double)VOL4;
        const double l1        = r1[0] / N;
        const double ssim_mean = r2[0] / N;
        const double ssim_loss = 1.0 - ssim_mean;
        out[0] = (float)(l1 + 0.5 * ssim_loss);  // total
        out[1] = (float)l1;                      // l1_loss
        out[2] = (float)ssim_loss;               // ssim_loss
        out[3] = 0.f;                            // reg_loss
    }
}

extern "C" void kernel_launch(void* const* d_in, const int* in_sizes, int n_in,
                              void* d_out, int out_size, void* d_ws, size_t ws_size,
                              hipStream_t stream)
{
    const float* pred = (const float*)d_in[0];
    const float* targ = (const float*)d_in[1];
    float* out = (float*)d_out;

    _Float16* G0 = (_Float16*)d_ws;                 // 2*VOL4 f16 = 33.6 MB
    _Float16* G1 = G0 + 2 * (size_t)VOL4;           // 33.6 MB
    float* l1p   = (float*)((char*)d_ws + (size_t)8 * VOL4);
    float* ssimp = l1p + K1_BLOCKS;

    k_wh<<<K1_BLOCKS, 256, 0, stream>>>(pred, targ, G0, G1, l1p);
    k_d_ssim<<<K2_BLOCKS, 256, 0, stream>>>(G0, G1, ssimp);
    k_final<<<1, 256, 0, stream>>>(l1p, ssimp, out);
}